// Round 6
// baseline (358.580 us; speedup 1.0000x reference)
//
#include <hip/hip_runtime.h>
#include <hip/hip_bf16.h>

// BlockNonLocal: B=2, C=64, N=8192.
// z = W @ softmax(x^T x) x^T + bias + x  per batch.  fp32 I/O, bf16 MFMA.
// Round 6: latency-bound fix. 16 q-rows/wave -> 1024 blocks (4/CU, 16 waves/CU);
// removed the lgkmcnt(0)+sched_barrier wall (per-wave DS FIFO orders write->read);
// s_setprio around MFMA clusters (independent blocks = phase-diverse waves).

constexpr int NC = 64;
constexpr int NN = 8192;
constexpr int NKV = 128;       // 64-wide KV tiles

typedef __attribute__((ext_vector_type(8))) short bf16x8;
typedef __attribute__((ext_vector_type(4))) float f32x4;

static __device__ __forceinline__ short f2bf(float f) {
    union { float f; unsigned u; } v; v.f = f;
    unsigned r = v.u + 0x7FFFu + ((v.u >> 16) & 1u);
    return (short)(r >> 16);
}
static __device__ __forceinline__ float bf2f(short h) {
    union { unsigned u; float f; } v;
    v.u = ((unsigned)(unsigned short)h) << 16;
    return v.f;
}

// ---------------------------------------------------------------------------
// Prep: x fp32 [b][c][j] -> Xcj bf16 (same layout) and Xjc bf16 ([b][j][c]).
// grid (128, 2), 256 threads; one 64x64 tile per block.
// ---------------------------------------------------------------------------
__global__ __launch_bounds__(256) void prep_kernel(
    const float* __restrict__ x, short* __restrict__ Xjc, short* __restrict__ Xcj)
{
    __shared__ short T[64 * 64];   // [j][c], xor-swizzled
    const int tid = threadIdx.x;
    const int jt = blockIdx.x;     // j-tile 0..127
    const int b  = blockIdx.y;
    const int bo = b * NC * NN;
    const int sc = tid >> 2, sq = tid & 3;

    const float* xr = x + bo + sc * NN + jt * 64 + sq * 16;
    float fl[16];
    *(float4*)&fl[0]  = *(const float4*)(xr + 0);
    *(float4*)&fl[4]  = *(const float4*)(xr + 4);
    *(float4*)&fl[8]  = *(const float4*)(xr + 8);
    *(float4*)&fl[12] = *(const float4*)(xr + 12);
    short h[16];
    #pragma unroll
    for (int e = 0; e < 16; ++e) h[e] = f2bf(fl[e]);

    bf16x8 v0, v1;
    #pragma unroll
    for (int e = 0; e < 8; ++e) { v0[e] = h[e]; v1[e] = h[8 + e]; }
    *(bf16x8*)&Xcj[bo + sc * NN + jt * 64 + sq * 16]     = v0;
    *(bf16x8*)&Xcj[bo + sc * NN + jt * 64 + sq * 16 + 8] = v1;

    #pragma unroll
    for (int jj = 0; jj < 16; ++jj) {
        int j = sq * 16 + jj;
        T[(j * 64 + sc) ^ ((j & 7) << 3)] = h[jj];
    }
    __syncthreads();

    const int jr = tid >> 2, cq = tid & 3;
    bf16x8 a0 = *(const bf16x8*)&T[(jr * 64 + cq * 16) ^ ((jr & 7) << 3)];
    bf16x8 a1 = *(const bf16x8*)&T[(jr * 64 + cq * 16 + 8) ^ ((jr & 7) << 3)];
    *(bf16x8*)&Xjc[bo + (jt * 64 + jr) * 64 + cq * 16]     = a0;
    *(bf16x8*)&Xjc[bo + (jt * 64 + jr) * 64 + cq * 16 + 8] = a1;
}

// ---------------------------------------------------------------------------
// Flash-decoding attention partials. grid (128, 2, nsplit), 256 threads.
// Each wave owns 16 q rows. No barriers; K/V fragments read from global.
// ---------------------------------------------------------------------------
__global__ __launch_bounds__(256, 4) void attn_fd_kernel(
    const short* __restrict__ Xjc, const short* __restrict__ Xcj,
    float* __restrict__ ypart, float* __restrict__ lpart, int tps)
{
    __shared__ short Pl[4][16 * 64];   // per-wave P, xor-swizzled

    const int tid  = threadIdx.x;
    const int lane = tid & 63;
    const int wv   = tid >> 6;
    const int lo   = lane & 15;
    const int hi   = lane >> 4;

    const int b  = blockIdx.y;
    const int sp = blockIdx.z;
    const int bo = b * NC * NN;
    const int qbase = blockIdx.x * 64 + wv * 16;
    short* Pw = Pl[wv];

    // Q fragments: (lane,e) -> Q[qbase+lo][c], c = kk*32 + hi*8 + e
    bf16x8 qf[2];
    #pragma unroll
    for (int kk = 0; kk < 2; ++kk)
        qf[kk] = *(const bf16x8*)&Xjc[bo + (qbase + lo) * 64 + kk * 32 + hi * 8];

    // fixed per-row shift m_i = ||q_i||^2 (bf16-rounded q; any nearby shift works)
    float mrow[4];
    {
        float v = 0.0f;
        #pragma unroll
        for (int kk = 0; kk < 2; ++kk)
            #pragma unroll
            for (int e = 0; e < 8; ++e) { float q = bf2f(qf[kk][e]); v += q * q; }
        v += __shfl_xor(v, 16);
        v += __shfl_xor(v, 32);        // lanes sharing lo now hold full ||q||^2
        #pragma unroll
        for (int r = 0; r < 4; ++r) mrow[r] = __shfl(v, hi * 4 + r);
    }

    f32x4 acc[4];    // y^T fragments
    f32x4 lacc;      // row-sum accumulator (ones-MFMA)
    #pragma unroll
    for (int ct = 0; ct < 4; ++ct)
        #pragma unroll
        for (int r = 0; r < 4; ++r) acc[ct][r] = 0.0f;
    #pragma unroll
    for (int r = 0; r < 4; ++r) lacc[r] = 0.0f;
    bf16x8 ones;
    #pragma unroll
    for (int e = 0; e < 8; ++e) ones[e] = (short)0x3F80;   // bf16 1.0

    const int jb0 = sp * tps, jb1 = jb0 + tps;
    bf16x8 kfc[4][2], kfn[4][2];
    #pragma unroll
    for (int jt = 0; jt < 4; ++jt)
        #pragma unroll
        for (int kk = 0; kk < 2; ++kk)
            kfc[jt][kk] = *(const bf16x8*)&Xjc[bo + (jb0 * 64 + jt * 16 + lo) * 64 + kk * 32 + hi * 8];

    for (int jb = jb0; jb < jb1; ++jb) {
        // V fragments for this tile (consumed after softmax -> latency hidden)
        bf16x8 vf[4][2];
        #pragma unroll
        for (int ct = 0; ct < 4; ++ct)
            #pragma unroll
            for (int kk = 0; kk < 2; ++kk)
                vf[ct][kk] = *(const bf16x8*)&Xcj[bo + (ct * 16 + lo) * NN + jb * 64 + kk * 32 + hi * 8];
        // prefetch next tile's K fragments
        const bool more = (jb + 1 < jb1);
        if (more) {
            #pragma unroll
            for (int jt = 0; jt < 4; ++jt)
                #pragma unroll
                for (int kk = 0; kk < 2; ++kk)
                    kfn[jt][kk] = *(const bf16x8*)&Xjc[bo + ((jb + 1) * 64 + jt * 16 + lo) * 64 + kk * 32 + hi * 8];
        }

        // QK^T: s[jt][r] = S[i = hi*4+r][j = jb*64 + jt*16+lo]
        f32x4 s[4];
        __builtin_amdgcn_s_setprio(1);
        #pragma unroll
        for (int jt = 0; jt < 4; ++jt) {
            #pragma unroll
            for (int r = 0; r < 4; ++r) s[jt][r] = 0.0f;
            #pragma unroll
            for (int kk = 0; kk < 2; ++kk)
                s[jt] = __builtin_amdgcn_mfma_f32_16x16x32_bf16(qf[kk], kfc[jt][kk], s[jt], 0, 0, 0);
        }
        __builtin_amdgcn_s_setprio(0);

        // P = exp(S - m), straight to LDS (no reductions, no rescale).
        // Same-wave DS FIFO orders these writes before the reads below —
        // no lgkmcnt(0)/sched_barrier wall, so the scheduler can pipeline.
        #pragma unroll
        for (int jt = 0; jt < 4; ++jt)
            #pragma unroll
            for (int r = 0; r < 4; ++r) {
                float p = __expf(s[jt][r] - mrow[r]);
                int i = hi * 4 + r;
                Pw[(i * 64 + jt * 16 + lo) ^ ((i & 7) << 3)] = f2bf(p);
            }

        // P^T B-fragments
        bf16x8 pf[2];
        #pragma unroll
        for (int kk = 0; kk < 2; ++kk)
            pf[kk] = *(const bf16x8*)&Pw[(lo * 64 + kk * 32 + hi * 8) ^ ((lo & 7) << 3)];

        __builtin_amdgcn_s_setprio(1);
        // l += ones * P^T   (row-sum via MFMA)
        #pragma unroll
        for (int kk = 0; kk < 2; ++kk)
            lacc = __builtin_amdgcn_mfma_f32_16x16x32_bf16(ones, pf[kk], lacc, 0, 0, 0);

        // y^T += V^T * P^T
        #pragma unroll
        for (int ct = 0; ct < 4; ++ct)
            #pragma unroll
            for (int kk = 0; kk < 2; ++kk)
                acc[ct] = __builtin_amdgcn_mfma_f32_16x16x32_bf16(vf[ct][kk], pf[kk], acc[ct], 0, 0, 0);
        __builtin_amdgcn_s_setprio(0);

        if (more) {
            #pragma unroll
            for (int jt = 0; jt < 4; ++jt)
                #pragma unroll
                for (int kk = 0; kk < 2; ++kk)
                    kfc[jt][kk] = kfn[jt][kk];
        }
    }

    // write partials: y^T [sp][b][c][N] and l [sp][b][N]
    float* yp = ypart + (size_t)(sp * 2 + b) * NC * NN;
    #pragma unroll
    for (int ct = 0; ct < 4; ++ct)
        #pragma unroll
        for (int r = 0; r < 4; ++r) {
            int c = ct * 16 + hi * 4 + r;
            yp[c * NN + qbase + lo] = acc[ct][r];
        }
    if (hi == 0)
        lpart[(sp * 2 + b) * NN + qbase + lo] = lacc[0];
}

// ---------------------------------------------------------------------------
// Combine: sum splits (shared shift => additive), normalize, 1x1 conv + bias
// + residual. grid (128, 2), 256 threads.
// ---------------------------------------------------------------------------
__global__ __launch_bounds__(256) void combine_kernel(
    const float* __restrict__ x, const float* __restrict__ wmat,
    const float* __restrict__ wbias, const float* __restrict__ ypart,
    const float* __restrict__ lpart, float* __restrict__ out, int nsplit)
{
    const int tid  = threadIdx.x;
    const int lane = tid & 63;
    const int wv   = tid >> 6;
    const int lo   = lane & 15;
    const int hi   = lane >> 4;

    const int batch = blockIdx.y;
    const int b_off = batch * NC * NN;
    const int qwave = blockIdx.x * 64 + wv * 16;
    const int i     = qwave + lo;

    float L = 0.0f;
    for (int s = 0; s < nsplit; ++s) L += lpart[(s * 2 + batch) * NN + i];
    const float linv = 1.0f / L;

    float accm[4][4];
    #pragma unroll
    for (int ct = 0; ct < 4; ++ct)
        #pragma unroll
        for (int r = 0; r < 4; ++r) accm[ct][r] = 0.0f;
    for (int s = 0; s < nsplit; ++s) {
        const float* yp = ypart + (size_t)(s * 2 + batch) * NC * NN;
        #pragma unroll
        for (int ct = 0; ct < 4; ++ct)
            #pragma unroll
            for (int r = 0; r < 4; ++r) {
                int c = ct * 16 + hi * 4 + r;
                accm[ct][r] += yp[c * NN + qwave + lo];
            }
    }

    // fused 1x1 conv via MFMA (c-map: c = kk*32 + (e>>2)*16 + hi*4 + (e&3))
    bf16x8 yf[2];
    #pragma unroll
    for (int kk = 0; kk < 2; ++kk)
        #pragma unroll
        for (int e = 0; e < 8; ++e)
            yf[kk][e] = f2bf(accm[kk * 2 + (e >> 2)][e & 3] * linv);

    f32x4 z[4];
    #pragma unroll
    for (int ot = 0; ot < 4; ++ot) {
        #pragma unroll
        for (int r = 0; r < 4; ++r) z[ot][r] = 0.0f;
        int o = ot * 16 + lo;
        #pragma unroll
        for (int kk = 0; kk < 2; ++kk) {
            float4 wa = *(const float4*)&wmat[o * 64 + kk * 32 + hi * 4];
            float4 wb = *(const float4*)&wmat[o * 64 + kk * 32 + 16 + hi * 4];
            bf16x8 wf;
            wf[0] = f2bf(wa.x); wf[1] = f2bf(wa.y); wf[2] = f2bf(wa.z); wf[3] = f2bf(wa.w);
            wf[4] = f2bf(wb.x); wf[5] = f2bf(wb.y); wf[6] = f2bf(wb.z); wf[7] = f2bf(wb.w);
            z[ot] = __builtin_amdgcn_mfma_f32_16x16x32_bf16(wf, yf[kk], z[ot], 0, 0, 0);
        }
    }

    #pragma unroll
    for (int ot = 0; ot < 4; ++ot)
        #pragma unroll
        for (int r = 0; r < 4; ++r) {
            int o = ot * 16 + hi * 4 + r;
            int idx = b_off + o * NN + qwave + lo;
            out[idx] = z[ot][r] + wbias[o] + x[idx];
        }
}

// ---------------------------------------------------------------------------
// Ultimate fallback (no workspace): round-1 single-kernel path.
// ---------------------------------------------------------------------------
__global__ __launch_bounds__(256) void attn_nl_kernel(
    const float* __restrict__ x, const float* __restrict__ wmat,
    const float* __restrict__ wbias, float* __restrict__ out)
{
    __shared__ short Xcj[64 * 64];
    __shared__ short Xjc[64 * 64];
    __shared__ short Plds[4][16 * 64];

    const int tid  = threadIdx.x;
    const int lane = tid & 63;
    const int wv   = tid >> 6;
    const int lo   = lane & 15;
    const int hi   = lane >> 4;

    const int batch = blockIdx.y;
    const int b_off = batch * NC * NN;
    const int qwave = blockIdx.x * 64 + wv * 16;
    const int qrow  = qwave + lo;

    bf16x8 qf[2];
    #pragma unroll
    for (int kk = 0; kk < 2; ++kk)
        #pragma unroll
        for (int e = 0; e < 8; ++e) {
            int c = kk * 32 + hi * 8 + e;
            qf[kk][e] = f2bf(x[b_off + c * NN + qrow]);
        }

    f32x4 acc[4];
    #pragma unroll
    for (int ct = 0; ct < 4; ++ct)
        #pragma unroll
        for (int r = 0; r < 4; ++r) acc[ct][r] = 0.0f;
    float mrow[4], lrow[4];
    #pragma unroll
    for (int r = 0; r < 4; ++r) { mrow[r] = -INFINITY; lrow[r] = 0.0f; }

    const int sc = tid >> 2;
    const int sq = tid & 3;
    const float* xrow = x + b_off + sc * NN + sq * 16;

    for (int jb = 0; jb < NKV; ++jb) {
        const int jbase = jb * 64;
        __syncthreads();

        float fl[16];
        *(float4*)&fl[0]  = *(const float4*)(xrow + jbase + 0);
        *(float4*)&fl[4]  = *(const float4*)(xrow + jbase + 4);
        *(float4*)&fl[8]  = *(const float4*)(xrow + jbase + 8);
        *(float4*)&fl[12] = *(const float4*)(xrow + jbase + 12);
        short h[16];
        #pragma unroll
        for (int e = 0; e < 16; ++e) h[e] = f2bf(fl[e]);

        {
            bf16x8 v0, v1;
            #pragma unroll
            for (int e = 0; e < 8; ++e) { v0[e] = h[e]; v1[e] = h[8 + e]; }
            int base = sc * 64 + sq * 16;
            int sw = (sc & 7) << 3;
            *(bf16x8*)&Xcj[(base) ^ sw]     = v0;
            *(bf16x8*)&Xcj[(base + 8) ^ sw] = v1;
        }
        #pragma unroll
        for (int jj = 0; jj < 16; ++jj) {
            int j = sq * 16 + jj;
            Xjc[(j * 64 + sc) ^ ((j & 7) << 3)] = h[jj];
        }
        __syncthreads();

        f32x4 s[4];
        #pragma unroll
        for (int jt = 0; jt < 4; ++jt) {
            #pragma unroll
            for (int r = 0; r < 4; ++r) s[jt][r] = 0.0f;
            int j = jt * 16 + lo;
            #pragma unroll
            for (int kk = 0; kk < 2; ++kk) {
                bf16x8 kf = *(const bf16x8*)&Xjc[(j * 64 + kk * 32 + hi * 8) ^ ((j & 7) << 3)];
                s[jt] = __builtin_amdgcn_mfma_f32_16x16x32_bf16(qf[kk], kf, s[jt], 0, 0, 0);
            }
        }

        float tm[4];
        #pragma unroll
        for (int r = 0; r < 4; ++r)
            tm[r] = fmaxf(fmaxf(s[0][r], s[1][r]), fmaxf(s[2][r], s[3][r]));
        #pragma unroll
        for (int d = 1; d < 16; d <<= 1)
            #pragma unroll
            for (int r = 0; r < 4; ++r)
                tm[r] = fmaxf(tm[r], __shfl_xor(tm[r], d));

        float scl4[4];
        #pragma unroll
        for (int r = 0; r < 4; ++r) {
            float mnew = fmaxf(mrow[r], tm[r]);
            scl4[r] = __expf(mrow[r] - mnew);
            mrow[r] = mnew;
        }

        float rs[4] = {0.f, 0.f, 0.f, 0.f};
        #pragma unroll
        for (int jt = 0; jt < 4; ++jt)
            #pragma unroll
            for (int r = 0; r < 4; ++r) {
                float p = __expf(s[jt][r] - mrow[r]);
                rs[r] += p;
                int i = hi * 4 + r;
                Plds[wv][(i * 64 + jt * 16 + lo) ^ ((i & 7) << 3)] = f2bf(p);
            }
        #pragma unroll
        for (int d = 1; d < 16; d <<= 1)
            #pragma unroll
            for (int r = 0; r < 4; ++r)
                rs[r] += __shfl_xor(rs[r], d);
        #pragma unroll
        for (int r = 0; r < 4; ++r)
            lrow[r] = lrow[r] * scl4[r] + rs[r];

        {
            int srcl = (lo >> 2) << 4;
            float b0 = __shfl(scl4[0], srcl), b1 = __shfl(scl4[1], srcl);
            float b2 = __shfl(scl4[2], srcl), b3 = __shfl(scl4[3], srcl);
            int rr = lo & 3;
            float scl = rr == 0 ? b0 : rr == 1 ? b1 : rr == 2 ? b2 : b3;
            #pragma unroll
            for (int ct = 0; ct < 4; ++ct)
                #pragma unroll
                for (int r = 0; r < 4; ++r) acc[ct][r] *= scl;
        }

        asm volatile("s_waitcnt lgkmcnt(0)" ::: "memory");

        bf16x8 pf[2];
        #pragma unroll
        for (int kk = 0; kk < 2; ++kk)
            pf[kk] = *(const bf16x8*)&Plds[wv][(lo * 64 + kk * 32 + hi * 8) ^ ((lo & 7) << 3)];
        #pragma unroll
        for (int ct = 0; ct < 4; ++ct) {
            int c = ct * 16 + lo;
            #pragma unroll
            for (int kk = 0; kk < 2; ++kk) {
                bf16x8 vf = *(const bf16x8*)&Xcj[(c * 64 + kk * 32 + hi * 8) ^ ((c & 7) << 3)];
                acc[ct] = __builtin_amdgcn_mfma_f32_16x16x32_bf16(vf, pf[kk], acc[ct], 0, 0, 0);
            }
        }
    }

    float linv;
    {
        int srcl = (lo >> 2) << 4;
        float c0 = __shfl(lrow[0], srcl), c1 = __shfl(lrow[1], srcl);
        float c2 = __shfl(lrow[2], srcl), c3 = __shfl(lrow[3], srcl);
        int rr = lo & 3;
        float li = rr == 0 ? c0 : rr == 1 ? c1 : rr == 2 ? c2 : c3;
        linv = 1.0f / li;
    }

    bf16x8 yf[2];
    #pragma unroll
    for (int kk = 0; kk < 2; ++kk)
        #pragma unroll
        for (int e = 0; e < 8; ++e)
            yf[kk][e] = f2bf(acc[kk * 2 + (e >> 2)][e & 3] * linv);

    f32x4 z[4];
    #pragma unroll
    for (int ot = 0; ot < 4; ++ot) {
        #pragma unroll
        for (int r = 0; r < 4; ++r) z[ot][r] = 0.0f;
        int o = ot * 16 + lo;
        #pragma unroll
        for (int kk = 0; kk < 2; ++kk) {
            float4 wa = *(const float4*)&wmat[o * 64 + kk * 32 + hi * 4];
            float4 wb = *(const float4*)&wmat[o * 64 + kk * 32 + 16 + hi * 4];
            bf16x8 wf;
            wf[0] = f2bf(wa.x); wf[1] = f2bf(wa.y); wf[2] = f2bf(wa.z); wf[3] = f2bf(wa.w);
            wf[4] = f2bf(wb.x); wf[5] = f2bf(wb.y); wf[6] = f2bf(wb.z); wf[7] = f2bf(wb.w);
            z[ot] = __builtin_amdgcn_mfma_f32_16x16x32_bf16(wf, yf[kk], z[ot], 0, 0, 0);
        }
    }

    #pragma unroll
    for (int ot = 0; ot < 4; ++ot)
        #pragma unroll
        for (int r = 0; r < 4; ++r) {
            int o = ot * 16 + hi * 4 + r;
            int idx = b_off + o * NN + qwave + lo;
            out[idx] = z[ot][r] + wbias[o] + x[idx];
        }
}

extern "C" void kernel_launch(void* const* d_in, const int* in_sizes, int n_in,
                              void* d_out, int out_size, void* d_ws, size_t ws_size,
                              hipStream_t stream) {
    const float* x  = (const float*)d_in[0];
    const float* w  = (const float*)d_in[1];
    const float* b  = (const float*)d_in[2];
    float* out = (float*)d_out;

    const size_t xhalf = (size_t)2 * NC * NN;   // shorts per orientation (both batches)
    auto need = [&](int ns) -> size_t {
        return xhalf * 2 * sizeof(short)
             + (size_t)ns * 2 * NC * NN * sizeof(float)
             + (size_t)ns * 2 * NN * sizeof(float);
    };

    int ns = 0;
    if      (ws_size >= need(4)) ns = 4;
    else if (ws_size >= need(2)) ns = 2;
    else if (ws_size >= need(1)) ns = 1;

    if (ns) {
        short* Xjc = (short*)d_ws;
        short* Xcj = Xjc + xhalf;
        float* ypart = (float*)(Xcj + xhalf);
        float* lpart = ypart + (size_t)ns * 2 * NC * NN;
        const int tps = NKV / ns;
        prep_kernel<<<dim3(NKV, 2), 256, 0, stream>>>(x, Xjc, Xcj);
        attn_fd_kernel<<<dim3(NN / 64, 2, ns), 256, 0, stream>>>(Xjc, Xcj, ypart, lpart, tps);
        combine_kernel<<<dim3(NN / 64, 2), 256, 0, stream>>>(x, w, b, ypart, lpart, out, ns);
    } else {
        attn_nl_kernel<<<dim3(NN / 64, 2), 256, 0, stream>>>(x, w, b, out);
    }
}

// Round 7
// 298.852 us; speedup vs baseline: 1.1999x; 1.1999x over previous
//
#include <hip/hip_runtime.h>
#include <hip/hip_bf16.h>

// BlockNonLocal: B=2, C=64, N=8192.
// z = W @ softmax(x^T x) x^T + bias + x  per batch.  fp32 I/O, bf16 MFMA.
// Round 7: R6 grid (1024 blocks, 16 q-rows/wave) WITHOUT the register clamp.
// R6's __launch_bounds__(256,4) forced VGPR 150->64 => 125 MB scratch spill
// (WRITE_SIZE evidence) => 307us. Fix: plain launch_bounds(256) + single-buffer
// K reload placed right after QK^T (loads overlap softmax+PV; -32 VGPR).

constexpr int NC = 64;
constexpr int NN = 8192;
constexpr int NKV = 128;       // 64-wide KV tiles

typedef __attribute__((ext_vector_type(8))) short bf16x8;
typedef __attribute__((ext_vector_type(4))) float f32x4;

static __device__ __forceinline__ short f2bf(float f) {
    union { float f; unsigned u; } v; v.f = f;
    unsigned r = v.u + 0x7FFFu + ((v.u >> 16) & 1u);
    return (short)(r >> 16);
}
static __device__ __forceinline__ float bf2f(short h) {
    union { unsigned u; float f; } v;
    v.u = ((unsigned)(unsigned short)h) << 16;
    return v.f;
}

// ---------------------------------------------------------------------------
// Prep: x fp32 [b][c][j] -> Xcj bf16 (same layout) and Xjc bf16 ([b][j][c]).
// grid (128, 2), 256 threads; one 64x64 tile per block.
// ---------------------------------------------------------------------------
__global__ __launch_bounds__(256) void prep_kernel(
    const float* __restrict__ x, short* __restrict__ Xjc, short* __restrict__ Xcj)
{
    __shared__ short T[64 * 64];   // [j][c], xor-swizzled
    const int tid = threadIdx.x;
    const int jt = blockIdx.x;     // j-tile 0..127
    const int b  = blockIdx.y;
    const int bo = b * NC * NN;
    const int sc = tid >> 2, sq = tid & 3;

    const float* xr = x + bo + sc * NN + jt * 64 + sq * 16;
    float fl[16];
    *(float4*)&fl[0]  = *(const float4*)(xr + 0);
    *(float4*)&fl[4]  = *(const float4*)(xr + 4);
    *(float4*)&fl[8]  = *(const float4*)(xr + 8);
    *(float4*)&fl[12] = *(const float4*)(xr + 12);
    short h[16];
    #pragma unroll
    for (int e = 0; e < 16; ++e) h[e] = f2bf(fl[e]);

    bf16x8 v0, v1;
    #pragma unroll
    for (int e = 0; e < 8; ++e) { v0[e] = h[e]; v1[e] = h[8 + e]; }
    *(bf16x8*)&Xcj[bo + sc * NN + jt * 64 + sq * 16]     = v0;
    *(bf16x8*)&Xcj[bo + sc * NN + jt * 64 + sq * 16 + 8] = v1;

    #pragma unroll
    for (int jj = 0; jj < 16; ++jj) {
        int j = sq * 16 + jj;
        T[(j * 64 + sc) ^ ((j & 7) << 3)] = h[jj];
    }
    __syncthreads();

    const int jr = tid >> 2, cq = tid & 3;
    bf16x8 a0 = *(const bf16x8*)&T[(jr * 64 + cq * 16) ^ ((jr & 7) << 3)];
    bf16x8 a1 = *(const bf16x8*)&T[(jr * 64 + cq * 16 + 8) ^ ((jr & 7) << 3)];
    *(bf16x8*)&Xjc[bo + (jt * 64 + jr) * 64 + cq * 16]     = a0;
    *(bf16x8*)&Xjc[bo + (jt * 64 + jr) * 64 + cq * 16 + 8] = a1;
}

// ---------------------------------------------------------------------------
// Flash-decoding attention partials. grid (128, 2, nsplit), 256 threads.
// Each wave owns 16 q rows. No barriers; K/V fragments read from global.
// ---------------------------------------------------------------------------
__global__ __launch_bounds__(256) void attn_fd_kernel(
    const short* __restrict__ Xjc, const short* __restrict__ Xcj,
    float* __restrict__ ypart, float* __restrict__ lpart, int tps)
{
    __shared__ short Pl[4][16 * 64];   // per-wave P, xor-swizzled

    const int tid  = threadIdx.x;
    const int lane = tid & 63;
    const int wv   = tid >> 6;
    const int lo   = lane & 15;
    const int hi   = lane >> 4;

    const int b  = blockIdx.y;
    const int sp = blockIdx.z;
    const int bo = b * NC * NN;
    const int qbase = blockIdx.x * 64 + wv * 16;
    short* Pw = Pl[wv];

    // Q fragments: (lane,e) -> Q[qbase+lo][c], c = kk*32 + hi*8 + e
    bf16x8 qf[2];
    #pragma unroll
    for (int kk = 0; kk < 2; ++kk)
        qf[kk] = *(const bf16x8*)&Xjc[bo + (qbase + lo) * 64 + kk * 32 + hi * 8];

    // fixed per-row shift m_i = ||q_i||^2 (bf16-rounded q; any nearby shift works)
    float mrow[4];
    {
        float v = 0.0f;
        #pragma unroll
        for (int kk = 0; kk < 2; ++kk)
            #pragma unroll
            for (int e = 0; e < 8; ++e) { float q = bf2f(qf[kk][e]); v += q * q; }
        v += __shfl_xor(v, 16);
        v += __shfl_xor(v, 32);        // lanes sharing lo now hold full ||q||^2
        #pragma unroll
        for (int r = 0; r < 4; ++r) mrow[r] = __shfl(v, hi * 4 + r);
    }

    f32x4 acc[4];    // y^T fragments
    f32x4 lacc;      // row-sum accumulator (ones-MFMA)
    #pragma unroll
    for (int ct = 0; ct < 4; ++ct)
        #pragma unroll
        for (int r = 0; r < 4; ++r) acc[ct][r] = 0.0f;
    #pragma unroll
    for (int r = 0; r < 4; ++r) lacc[r] = 0.0f;
    bf16x8 ones;
    #pragma unroll
    for (int e = 0; e < 8; ++e) ones[e] = (short)0x3F80;   // bf16 1.0

    const int jb0 = sp * tps, jb1 = jb0 + tps;
    // single-buffered K fragments; reloaded in place right after QK^T
    bf16x8 kfc[4][2];
    #pragma unroll
    for (int jt = 0; jt < 4; ++jt)
        #pragma unroll
        for (int kk = 0; kk < 2; ++kk)
            kfc[jt][kk] = *(const bf16x8*)&Xjc[bo + (jb0 * 64 + jt * 16 + lo) * 64 + kk * 32 + hi * 8];

    for (int jb = jb0; jb < jb1; ++jb) {
        // V fragments for this tile (consumed at end of iter -> latency hidden)
        bf16x8 vf[4][2];
        #pragma unroll
        for (int ct = 0; ct < 4; ++ct)
            #pragma unroll
            for (int kk = 0; kk < 2; ++kk)
                vf[ct][kk] = *(const bf16x8*)&Xcj[bo + (ct * 16 + lo) * NN + jb * 64 + kk * 32 + hi * 8];

        // QK^T: s[jt][r] = S[i = hi*4+r][j = jb*64 + jt*16+lo]
        f32x4 s[4];
        __builtin_amdgcn_s_setprio(1);
        #pragma unroll
        for (int jt = 0; jt < 4; ++jt) {
            #pragma unroll
            for (int r = 0; r < 4; ++r) s[jt][r] = 0.0f;
            #pragma unroll
            for (int kk = 0; kk < 2; ++kk)
                s[jt] = __builtin_amdgcn_mfma_f32_16x16x32_bf16(qf[kk], kfc[jt][kk], s[jt], 0, 0, 0);
        }
        __builtin_amdgcn_s_setprio(0);

        // kfc consumed -> refill in place for jb+1; loads overlap softmax+PV
        const bool more = (jb + 1 < jb1);
        if (more) {
            #pragma unroll
            for (int jt = 0; jt < 4; ++jt)
                #pragma unroll
                for (int kk = 0; kk < 2; ++kk)
                    kfc[jt][kk] = *(const bf16x8*)&Xjc[bo + ((jb + 1) * 64 + jt * 16 + lo) * 64 + kk * 32 + hi * 8];
        }

        // P = exp(S - m), straight to LDS (no reductions, no rescale).
        // Same-wave DS FIFO orders these writes before the reads below.
        #pragma unroll
        for (int jt = 0; jt < 4; ++jt)
            #pragma unroll
            for (int r = 0; r < 4; ++r) {
                float p = __expf(s[jt][r] - mrow[r]);
                int i = hi * 4 + r;
                Pw[(i * 64 + jt * 16 + lo) ^ ((i & 7) << 3)] = f2bf(p);
            }

        // P^T B-fragments
        bf16x8 pf[2];
        #pragma unroll
        for (int kk = 0; kk < 2; ++kk)
            pf[kk] = *(const bf16x8*)&Pw[(lo * 64 + kk * 32 + hi * 8) ^ ((lo & 7) << 3)];

        __builtin_amdgcn_s_setprio(1);
        // l += ones * P^T   (row-sum via MFMA)
        #pragma unroll
        for (int kk = 0; kk < 2; ++kk)
            lacc = __builtin_amdgcn_mfma_f32_16x16x32_bf16(ones, pf[kk], lacc, 0, 0, 0);

        // y^T += V^T * P^T
        #pragma unroll
        for (int ct = 0; ct < 4; ++ct)
            #pragma unroll
            for (int kk = 0; kk < 2; ++kk)
                acc[ct] = __builtin_amdgcn_mfma_f32_16x16x32_bf16(vf[ct][kk], pf[kk], acc[ct], 0, 0, 0);
        __builtin_amdgcn_s_setprio(0);
    }

    // write partials: y^T [sp][b][c][N] and l [sp][b][N]
    float* yp = ypart + (size_t)(sp * 2 + b) * NC * NN;
    #pragma unroll
    for (int ct = 0; ct < 4; ++ct)
        #pragma unroll
        for (int r = 0; r < 4; ++r) {
            int c = ct * 16 + hi * 4 + r;
            yp[c * NN + qbase + lo] = acc[ct][r];
        }
    if (hi == 0)
        lpart[(sp * 2 + b) * NN + qbase + lo] = lacc[0];
}

// ---------------------------------------------------------------------------
// Combine: sum splits (shared shift => additive), normalize, 1x1 conv + bias
// + residual. grid (128, 2), 256 threads.
// ---------------------------------------------------------------------------
__global__ __launch_bounds__(256) void combine_kernel(
    const float* __restrict__ x, const float* __restrict__ wmat,
    const float* __restrict__ wbias, const float* __restrict__ ypart,
    const float* __restrict__ lpart, float* __restrict__ out, int nsplit)
{
    const int tid  = threadIdx.x;
    const int lane = tid & 63;
    const int wv   = tid >> 6;
    const int lo   = lane & 15;
    const int hi   = lane >> 4;

    const int batch = blockIdx.y;
    const int b_off = batch * NC * NN;
    const int qwave = blockIdx.x * 64 + wv * 16;
    const int i     = qwave + lo;

    float L = 0.0f;
    for (int s = 0; s < nsplit; ++s) L += lpart[(s * 2 + batch) * NN + i];
    const float linv = 1.0f / L;

    float accm[4][4];
    #pragma unroll
    for (int ct = 0; ct < 4; ++ct)
        #pragma unroll
        for (int r = 0; r < 4; ++r) accm[ct][r] = 0.0f;
    for (int s = 0; s < nsplit; ++s) {
        const float* yp = ypart + (size_t)(s * 2 + batch) * NC * NN;
        #pragma unroll
        for (int ct = 0; ct < 4; ++ct)
            #pragma unroll
            for (int r = 0; r < 4; ++r) {
                int c = ct * 16 + hi * 4 + r;
                accm[ct][r] += yp[c * NN + qwave + lo];
            }
    }

    // fused 1x1 conv via MFMA (c-map: c = kk*32 + (e>>2)*16 + hi*4 + (e&3))
    bf16x8 yf[2];
    #pragma unroll
    for (int kk = 0; kk < 2; ++kk)
        #pragma unroll
        for (int e = 0; e < 8; ++e)
            yf[kk][e] = f2bf(accm[kk * 2 + (e >> 2)][e & 3] * linv);

    f32x4 z[4];
    #pragma unroll
    for (int ot = 0; ot < 4; ++ot) {
        #pragma unroll
        for (int r = 0; r < 4; ++r) z[ot][r] = 0.0f;
        int o = ot * 16 + lo;
        #pragma unroll
        for (int kk = 0; kk < 2; ++kk) {
            float4 wa = *(const float4*)&wmat[o * 64 + kk * 32 + hi * 4];
            float4 wb = *(const float4*)&wmat[o * 64 + kk * 32 + 16 + hi * 4];
            bf16x8 wf;
            wf[0] = f2bf(wa.x); wf[1] = f2bf(wa.y); wf[2] = f2bf(wa.z); wf[3] = f2bf(wa.w);
            wf[4] = f2bf(wb.x); wf[5] = f2bf(wb.y); wf[6] = f2bf(wb.z); wf[7] = f2bf(wb.w);
            z[ot] = __builtin_amdgcn_mfma_f32_16x16x32_bf16(wf, yf[kk], z[ot], 0, 0, 0);
        }
    }

    #pragma unroll
    for (int ot = 0; ot < 4; ++ot)
        #pragma unroll
        for (int r = 0; r < 4; ++r) {
            int o = ot * 16 + hi * 4 + r;
            int idx = b_off + o * NN + qwave + lo;
            out[idx] = z[ot][r] + wbias[o] + x[idx];
        }
}

// ---------------------------------------------------------------------------
// Ultimate fallback (no workspace): round-1 single-kernel path.
// ---------------------------------------------------------------------------
__global__ __launch_bounds__(256) void attn_nl_kernel(
    const float* __restrict__ x, const float* __restrict__ wmat,
    const float* __restrict__ wbias, float* __restrict__ out)
{
    __shared__ short Xcj[64 * 64];
    __shared__ short Xjc[64 * 64];
    __shared__ short Plds[4][16 * 64];

    const int tid  = threadIdx.x;
    const int lane = tid & 63;
    const int wv   = tid >> 6;
    const int lo   = lane & 15;
    const int hi   = lane >> 4;

    const int batch = blockIdx.y;
    const int b_off = batch * NC * NN;
    const int qwave = blockIdx.x * 64 + wv * 16;
    const int qrow  = qwave + lo;

    bf16x8 qf[2];
    #pragma unroll
    for (int kk = 0; kk < 2; ++kk)
        #pragma unroll
        for (int e = 0; e < 8; ++e) {
            int c = kk * 32 + hi * 8 + e;
            qf[kk][e] = f2bf(x[b_off + c * NN + qrow]);
        }

    f32x4 acc[4];
    #pragma unroll
    for (int ct = 0; ct < 4; ++ct)
        #pragma unroll
        for (int r = 0; r < 4; ++r) acc[ct][r] = 0.0f;
    float mrow[4], lrow[4];
    #pragma unroll
    for (int r = 0; r < 4; ++r) { mrow[r] = -INFINITY; lrow[r] = 0.0f; }

    const int sc = tid >> 2;
    const int sq = tid & 3;
    const float* xrow = x + b_off + sc * NN + sq * 16;

    for (int jb = 0; jb < NKV; ++jb) {
        const int jbase = jb * 64;
        __syncthreads();

        float fl[16];
        *(float4*)&fl[0]  = *(const float4*)(xrow + jbase + 0);
        *(float4*)&fl[4]  = *(const float4*)(xrow + jbase + 4);
        *(float4*)&fl[8]  = *(const float4*)(xrow + jbase + 8);
        *(float4*)&fl[12] = *(const float4*)(xrow + jbase + 12);
        short h[16];
        #pragma unroll
        for (int e = 0; e < 16; ++e) h[e] = f2bf(fl[e]);

        {
            bf16x8 v0, v1;
            #pragma unroll
            for (int e = 0; e < 8; ++e) { v0[e] = h[e]; v1[e] = h[8 + e]; }
            int base = sc * 64 + sq * 16;
            int sw = (sc & 7) << 3;
            *(bf16x8*)&Xcj[(base) ^ sw]     = v0;
            *(bf16x8*)&Xcj[(base + 8) ^ sw] = v1;
        }
        #pragma unroll
        for (int jj = 0; jj < 16; ++jj) {
            int j = sq * 16 + jj;
            Xjc[(j * 64 + sc) ^ ((j & 7) << 3)] = h[jj];
        }
        __syncthreads();

        f32x4 s[4];
        #pragma unroll
        for (int jt = 0; jt < 4; ++jt) {
            #pragma unroll
            for (int r = 0; r < 4; ++r) s[jt][r] = 0.0f;
            int j = jt * 16 + lo;
            #pragma unroll
            for (int kk = 0; kk < 2; ++kk) {
                bf16x8 kf = *(const bf16x8*)&Xjc[(j * 64 + kk * 32 + hi * 8) ^ ((j & 7) << 3)];
                s[jt] = __builtin_amdgcn_mfma_f32_16x16x32_bf16(qf[kk], kf, s[jt], 0, 0, 0);
            }
        }

        float tm[4];
        #pragma unroll
        for (int r = 0; r < 4; ++r)
            tm[r] = fmaxf(fmaxf(s[0][r], s[1][r]), fmaxf(s[2][r], s[3][r]));
        #pragma unroll
        for (int d = 1; d < 16; d <<= 1)
            #pragma unroll
            for (int r = 0; r < 4; ++r)
                tm[r] = fmaxf(tm[r], __shfl_xor(tm[r], d));

        float scl4[4];
        #pragma unroll
        for (int r = 0; r < 4; ++r) {
            float mnew = fmaxf(mrow[r], tm[r]);
            scl4[r] = __expf(mrow[r] - mnew);
            mrow[r] = mnew;
        }

        float rs[4] = {0.f, 0.f, 0.f, 0.f};
        #pragma unroll
        for (int jt = 0; jt < 4; ++jt)
            #pragma unroll
            for (int r = 0; r < 4; ++r) {
                float p = __expf(s[jt][r] - mrow[r]);
                rs[r] += p;
                int i = hi * 4 + r;
                Plds[wv][(i * 64 + jt * 16 + lo) ^ ((i & 7) << 3)] = f2bf(p);
            }
        #pragma unroll
        for (int d = 1; d < 16; d <<= 1)
            #pragma unroll
            for (int r = 0; r < 4; ++r)
                rs[r] += __shfl_xor(rs[r], d);
        #pragma unroll
        for (int r = 0; r < 4; ++r)
            lrow[r] = lrow[r] * scl4[r] + rs[r];

        {
            int srcl = (lo >> 2) << 4;
            float b0 = __shfl(scl4[0], srcl), b1 = __shfl(scl4[1], srcl);
            float b2 = __shfl(scl4[2], srcl), b3 = __shfl(scl4[3], srcl);
            int rr = lo & 3;
            float scl = rr == 0 ? b0 : rr == 1 ? b1 : rr == 2 ? b2 : b3;
            #pragma unroll
            for (int ct = 0; ct < 4; ++ct)
                #pragma unroll
                for (int r = 0; r < 4; ++r) acc[ct][r] *= scl;
        }

        asm volatile("s_waitcnt lgkmcnt(0)" ::: "memory");

        bf16x8 pf[2];
        #pragma unroll
        for (int kk = 0; kk < 2; ++kk)
            pf[kk] = *(const bf16x8*)&Plds[wv][(lo * 64 + kk * 32 + hi * 8) ^ ((lo & 7) << 3)];
        #pragma unroll
        for (int ct = 0; ct < 4; ++ct) {
            int c = ct * 16 + lo;
            #pragma unroll
            for (int kk = 0; kk < 2; ++kk) {
                bf16x8 vf = *(const bf16x8*)&Xcj[(c * 64 + kk * 32 + hi * 8) ^ ((c & 7) << 3)];
                acc[ct] = __builtin_amdgcn_mfma_f32_16x16x32_bf16(vf, pf[kk], acc[ct], 0, 0, 0);
            }
        }
    }

    float linv;
    {
        int srcl = (lo >> 2) << 4;
        float c0 = __shfl(lrow[0], srcl), c1 = __shfl(lrow[1], srcl);
        float c2 = __shfl(lrow[2], srcl), c3 = __shfl(lrow[3], srcl);
        int rr = lo & 3;
        float li = rr == 0 ? c0 : rr == 1 ? c1 : rr == 2 ? c2 : c3;
        linv = 1.0f / li;
    }

    bf16x8 yf[2];
    #pragma unroll
    for (int kk = 0; kk < 2; ++kk)
        #pragma unroll
        for (int e = 0; e < 8; ++e)
            yf[kk][e] = f2bf(acc[kk * 2 + (e >> 2)][e & 3] * linv);

    f32x4 z[4];
    #pragma unroll
    for (int ot = 0; ot < 4; ++ot) {
        #pragma unroll
        for (int r = 0; r < 4; ++r) z[ot][r] = 0.0f;
        int o = ot * 16 + lo;
        #pragma unroll
        for (int kk = 0; kk < 2; ++kk) {
            float4 wa = *(const float4*)&wmat[o * 64 + kk * 32 + hi * 4];
            float4 wb = *(const float4*)&wmat[o * 64 + kk * 32 + 16 + hi * 4];
            bf16x8 wf;
            wf[0] = f2bf(wa.x); wf[1] = f2bf(wa.y); wf[2] = f2bf(wa.z); wf[3] = f2bf(wa.w);
            wf[4] = f2bf(wb.x); wf[5] = f2bf(wb.y); wf[6] = f2bf(wb.z); wf[7] = f2bf(wb.w);
            z[ot] = __builtin_amdgcn_mfma_f32_16x16x32_bf16(wf, yf[kk], z[ot], 0, 0, 0);
        }
    }

    #pragma unroll
    for (int ot = 0; ot < 4; ++ot)
        #pragma unroll
        for (int r = 0; r < 4; ++r) {
            int o = ot * 16 + hi * 4 + r;
            int idx = b_off + o * NN + qwave + lo;
            out[idx] = z[ot][r] + wbias[o] + x[idx];
        }
}

extern "C" void kernel_launch(void* const* d_in, const int* in_sizes, int n_in,
                              void* d_out, int out_size, void* d_ws, size_t ws_size,
                              hipStream_t stream) {
    const float* x  = (const float*)d_in[0];
    const float* w  = (const float*)d_in[1];
    const float* b  = (const float*)d_in[2];
    float* out = (float*)d_out;

    const size_t xhalf = (size_t)2 * NC * NN;   // shorts per orientation (both batches)
    auto need = [&](int ns) -> size_t {
        return xhalf * 2 * sizeof(short)
             + (size_t)ns * 2 * NC * NN * sizeof(float)
             + (size_t)ns * 2 * NN * sizeof(float);
    };

    int ns = 0;
    if      (ws_size >= need(4)) ns = 4;
    else if (ws_size >= need(2)) ns = 2;
    else if (ws_size >= need(1)) ns = 1;

    if (ns) {
        short* Xjc = (short*)d_ws;
        short* Xcj = Xjc + xhalf;
        float* ypart = (float*)(Xcj + xhalf);
        float* lpart = ypart + (size_t)ns * 2 * NC * NN;
        const int tps = NKV / ns;
        prep_kernel<<<dim3(NKV, 2), 256, 0, stream>>>(x, Xjc, Xcj);
        attn_fd_kernel<<<dim3(NN / 64, 2, ns), 256, 0, stream>>>(Xjc, Xcj, ypart, lpart, tps);
        combine_kernel<<<dim3(NN / 64, 2), 256, 0, stream>>>(x, w, b, ypart, lpart, out, ns);
    } else {
        attn_nl_kernel<<<dim3(NN / 64, 2), 256, 0, stream>>>(x, w, b, out);
    }
}

// Round 9
// 195.658 us; speedup vs baseline: 1.8327x; 1.5274x over previous
//
#include <hip/hip_runtime.h>
#include <hip/hip_bf16.h>

// BlockNonLocal: B=2, C=64, N=8192.
// z = W @ softmax(x^T x) x^T + bias + x  per batch.  fp32 I/O, bf16 MFMA.
// Round 8 resubmit (R8 bench was a broker acquisition timeout — no data):
// measured-best R5 attention body (qs=2 = 32 q-rows/wave, kfn double-buffer,
// lgkm wall; 130us, VGPR 124) + ONE lever: ns=8 splits -> 1024 blocks =
// 4 blocks/CU = 16 waves/CU (R5 was grid-limited at 2 blocks/CU).
// R7 lesson: halving rows/wave doubled per-iter fixed costs — work-per-wave
// beats wave count when latency-bound.

constexpr int NC = 64;
constexpr int NN = 8192;
constexpr int NKV = 128;       // 64-wide KV tiles

typedef __attribute__((ext_vector_type(8))) short bf16x8;
typedef __attribute__((ext_vector_type(4))) float f32x4;

static __device__ __forceinline__ short f2bf(float f) {
    union { float f; unsigned u; } v; v.f = f;
    unsigned r = v.u + 0x7FFFu + ((v.u >> 16) & 1u);
    return (short)(r >> 16);
}
static __device__ __forceinline__ float bf2f(short h) {
    union { unsigned u; float f; } v;
    v.u = ((unsigned)(unsigned short)h) << 16;
    return v.f;
}

// ---------------------------------------------------------------------------
// Prep: x fp32 [b][c][j] -> Xcj bf16 (same layout) and Xjc bf16 ([b][j][c]).
// grid (128, 2), 256 threads; one 64x64 tile per block.
// ---------------------------------------------------------------------------
__global__ __launch_bounds__(256) void prep_kernel(
    const float* __restrict__ x, short* __restrict__ Xjc, short* __restrict__ Xcj)
{
    __shared__ short T[64 * 64];   // [j][c], xor-swizzled
    const int tid = threadIdx.x;
    const int jt = blockIdx.x;     // j-tile 0..127
    const int b  = blockIdx.y;
    const int bo = b * NC * NN;
    const int sc = tid >> 2, sq = tid & 3;

    const float* xr = x + bo + sc * NN + jt * 64 + sq * 16;
    float fl[16];
    *(float4*)&fl[0]  = *(const float4*)(xr + 0);
    *(float4*)&fl[4]  = *(const float4*)(xr + 4);
    *(float4*)&fl[8]  = *(const float4*)(xr + 8);
    *(float4*)&fl[12] = *(const float4*)(xr + 12);
    short h[16];
    #pragma unroll
    for (int e = 0; e < 16; ++e) h[e] = f2bf(fl[e]);

    bf16x8 v0, v1;
    #pragma unroll
    for (int e = 0; e < 8; ++e) { v0[e] = h[e]; v1[e] = h[8 + e]; }
    *(bf16x8*)&Xcj[bo + sc * NN + jt * 64 + sq * 16]     = v0;
    *(bf16x8*)&Xcj[bo + sc * NN + jt * 64 + sq * 16 + 8] = v1;

    #pragma unroll
    for (int jj = 0; jj < 16; ++jj) {
        int j = sq * 16 + jj;
        T[(j * 64 + sc) ^ ((j & 7) << 3)] = h[jj];
    }
    __syncthreads();

    const int jr = tid >> 2, cq = tid & 3;
    bf16x8 a0 = *(const bf16x8*)&T[(jr * 64 + cq * 16) ^ ((jr & 7) << 3)];
    bf16x8 a1 = *(const bf16x8*)&T[(jr * 64 + cq * 16 + 8) ^ ((jr & 7) << 3)];
    *(bf16x8*)&Xjc[bo + (jt * 64 + jr) * 64 + cq * 16]     = a0;
    *(bf16x8*)&Xjc[bo + (jt * 64 + jr) * 64 + cq * 16 + 8] = a1;
}

// ---------------------------------------------------------------------------
// Flash-decoding attention partials. grid (64, 2, nsplit), 256 threads.
// Each wave owns 32 q rows. No barriers; K/V fragments read from global.
// (Byte-identical to the R5 body; only the launcher's nsplit changes.)
// ---------------------------------------------------------------------------
__global__ __launch_bounds__(256) void attn_fd_kernel(
    const short* __restrict__ Xjc, const short* __restrict__ Xcj,
    float* __restrict__ ypart, float* __restrict__ lpart, int tps)
{
    __shared__ short Pl[4][32 * 64];   // per-wave P, xor-swizzled

    const int tid  = threadIdx.x;
    const int lane = tid & 63;
    const int wv   = tid >> 6;
    const int lo   = lane & 15;
    const int hi   = lane >> 4;

    const int b  = blockIdx.y;
    const int sp = blockIdx.z;
    const int bo = b * NC * NN;
    const int qbase = blockIdx.x * 128 + wv * 32;
    short* Pw = Pl[wv];

    // Q fragments: (lane,e) -> Q[qbase+qs*16+lo][c], c = kk*32 + hi*8 + e
    bf16x8 qf[2][2];
    #pragma unroll
    for (int qs = 0; qs < 2; ++qs)
        #pragma unroll
        for (int kk = 0; kk < 2; ++kk)
            qf[qs][kk] = *(const bf16x8*)&Xjc[bo + (qbase + qs * 16 + lo) * 64 + kk * 32 + hi * 8];

    // fixed per-row shift m_i = ||q_i||^2 (bf16-rounded q; any nearby shift works)
    float mrow[2][4];
    #pragma unroll
    for (int qs = 0; qs < 2; ++qs) {
        float v = 0.0f;
        #pragma unroll
        for (int kk = 0; kk < 2; ++kk)
            #pragma unroll
            for (int e = 0; e < 8; ++e) { float q = bf2f(qf[qs][kk][e]); v += q * q; }
        v += __shfl_xor(v, 16);
        v += __shfl_xor(v, 32);        // lanes sharing lo now hold full ||q||^2
        #pragma unroll
        for (int r = 0; r < 4; ++r) mrow[qs][r] = __shfl(v, hi * 4 + r);
    }

    f32x4 acc[2][4];    // y^T fragments
    f32x4 lacc[2];      // row-sum accumulator (ones-MFMA)
    #pragma unroll
    for (int qs = 0; qs < 2; ++qs) {
        #pragma unroll
        for (int ct = 0; ct < 4; ++ct)
            #pragma unroll
            for (int r = 0; r < 4; ++r) acc[qs][ct][r] = 0.0f;
        #pragma unroll
        for (int r = 0; r < 4; ++r) lacc[qs][r] = 0.0f;
    }
    bf16x8 ones;
    #pragma unroll
    for (int e = 0; e < 8; ++e) ones[e] = (short)0x3F80;   // bf16 1.0

    const int jb0 = sp * tps, jb1 = jb0 + tps;
    bf16x8 kfc[4][2], kfn[4][2];
    #pragma unroll
    for (int jt = 0; jt < 4; ++jt)
        #pragma unroll
        for (int kk = 0; kk < 2; ++kk)
            kfc[jt][kk] = *(const bf16x8*)&Xjc[bo + (jb0 * 64 + jt * 16 + lo) * 64 + kk * 32 + hi * 8];

    for (int jb = jb0; jb < jb1; ++jb) {
        // V fragments for this tile (consumed after softmax -> latency hidden)
        bf16x8 vf[4][2];
        #pragma unroll
        for (int ct = 0; ct < 4; ++ct)
            #pragma unroll
            for (int kk = 0; kk < 2; ++kk)
                vf[ct][kk] = *(const bf16x8*)&Xcj[bo + (ct * 16 + lo) * NN + jb * 64 + kk * 32 + hi * 8];
        // prefetch next tile's K fragments
        const bool more = (jb + 1 < jb1);
        if (more) {
            #pragma unroll
            for (int jt = 0; jt < 4; ++jt)
                #pragma unroll
                for (int kk = 0; kk < 2; ++kk)
                    kfn[jt][kk] = *(const bf16x8*)&Xjc[bo + ((jb + 1) * 64 + jt * 16 + lo) * 64 + kk * 32 + hi * 8];
        }

        // QK^T: s[qs][jt][r] = S[i = qs*16+hi*4+r][j = jb*64 + jt*16+lo]
        f32x4 s[2][4];
        #pragma unroll
        for (int qs = 0; qs < 2; ++qs)
            #pragma unroll
            for (int jt = 0; jt < 4; ++jt) {
                #pragma unroll
                for (int r = 0; r < 4; ++r) s[qs][jt][r] = 0.0f;
                #pragma unroll
                for (int kk = 0; kk < 2; ++kk)
                    s[qs][jt] = __builtin_amdgcn_mfma_f32_16x16x32_bf16(qf[qs][kk], kfc[jt][kk], s[qs][jt], 0, 0, 0);
            }

        // P = exp(S - m), straight to LDS (no reductions, no rescale)
        #pragma unroll
        for (int qs = 0; qs < 2; ++qs)
            #pragma unroll
            for (int jt = 0; jt < 4; ++jt)
                #pragma unroll
                for (int r = 0; r < 4; ++r) {
                    float p = __expf(s[qs][jt][r] - mrow[qs][r]);
                    int i = qs * 16 + hi * 4 + r;
                    Pw[(i * 64 + jt * 16 + lo) ^ ((i & 7) << 3)] = f2bf(p);
                }
        asm volatile("s_waitcnt lgkmcnt(0)" ::: "memory");
        __builtin_amdgcn_sched_barrier(0);

        // P^T B-fragments
        bf16x8 pf[2][2];
        #pragma unroll
        for (int qs = 0; qs < 2; ++qs)
            #pragma unroll
            for (int kk = 0; kk < 2; ++kk) {
                int row = qs * 16 + lo;
                pf[qs][kk] = *(const bf16x8*)&Pw[(row * 64 + kk * 32 + hi * 8) ^ ((row & 7) << 3)];
            }

        // l += ones * P^T   (row-sum via MFMA)
        #pragma unroll
        for (int qs = 0; qs < 2; ++qs)
            #pragma unroll
            for (int kk = 0; kk < 2; ++kk)
                lacc[qs] = __builtin_amdgcn_mfma_f32_16x16x32_bf16(ones, pf[qs][kk], lacc[qs], 0, 0, 0);

        // y^T += V^T * P^T
        #pragma unroll
        for (int qs = 0; qs < 2; ++qs)
            #pragma unroll
            for (int ct = 0; ct < 4; ++ct)
                #pragma unroll
                for (int kk = 0; kk < 2; ++kk)
                    acc[qs][ct] = __builtin_amdgcn_mfma_f32_16x16x32_bf16(vf[ct][kk], pf[qs][kk], acc[qs][ct], 0, 0, 0);

        if (more) {
            #pragma unroll
            for (int jt = 0; jt < 4; ++jt)
                #pragma unroll
                for (int kk = 0; kk < 2; ++kk)
                    kfc[jt][kk] = kfn[jt][kk];
        }
    }

    // write partials: y^T [sp][b][c][N] and l [sp][b][N]
    float* yp = ypart + (size_t)(sp * 2 + b) * NC * NN;
    #pragma unroll
    for (int qs = 0; qs < 2; ++qs)
        #pragma unroll
        for (int ct = 0; ct < 4; ++ct)
            #pragma unroll
            for (int r = 0; r < 4; ++r) {
                int c = ct * 16 + hi * 4 + r;
                yp[c * NN + qbase + qs * 16 + lo] = acc[qs][ct][r];
            }
    if (hi == 0) {
        #pragma unroll
        for (int qs = 0; qs < 2; ++qs)
            lpart[(sp * 2 + b) * NN + qbase + qs * 16 + lo] = lacc[qs][0];
    }
}

// ---------------------------------------------------------------------------
// Combine: sum splits (shared shift => additive), normalize, 1x1 conv + bias
// + residual. grid (128, 2), 256 threads.
// ---------------------------------------------------------------------------
__global__ __launch_bounds__(256) void combine_kernel(
    const float* __restrict__ x, const float* __restrict__ wmat,
    const float* __restrict__ wbias, const float* __restrict__ ypart,
    const float* __restrict__ lpart, float* __restrict__ out, int nsplit)
{
    const int tid  = threadIdx.x;
    const int lane = tid & 63;
    const int wv   = tid >> 6;
    const int lo   = lane & 15;
    const int hi   = lane >> 4;

    const int batch = blockIdx.y;
    const int b_off = batch * NC * NN;
    const int qwave = blockIdx.x * 64 + wv * 16;
    const int i     = qwave + lo;

    float L = 0.0f;
    for (int s = 0; s < nsplit; ++s) L += lpart[(s * 2 + batch) * NN + i];
    const float linv = 1.0f / L;

    float accm[4][4];
    #pragma unroll
    for (int ct = 0; ct < 4; ++ct)
        #pragma unroll
        for (int r = 0; r < 4; ++r) accm[ct][r] = 0.0f;
    for (int s = 0; s < nsplit; ++s) {
        const float* yp = ypart + (size_t)(s * 2 + batch) * NC * NN;
        #pragma unroll
        for (int ct = 0; ct < 4; ++ct)
            #pragma unroll
            for (int r = 0; r < 4; ++r) {
                int c = ct * 16 + hi * 4 + r;
                accm[ct][r] += yp[c * NN + qwave + lo];
            }
    }

    // fused 1x1 conv via MFMA (c-map: c = kk*32 + (e>>2)*16 + hi*4 + (e&3))
    bf16x8 yf[2];
    #pragma unroll
    for (int kk = 0; kk < 2; ++kk)
        #pragma unroll
        for (int e = 0; e < 8; ++e)
            yf[kk][e] = f2bf(accm[kk * 2 + (e >> 2)][e & 3] * linv);

    f32x4 z[4];
    #pragma unroll
    for (int ot = 0; ot < 4; ++ot) {
        #pragma unroll
        for (int r = 0; r < 4; ++r) z[ot][r] = 0.0f;
        int o = ot * 16 + lo;
        #pragma unroll
        for (int kk = 0; kk < 2; ++kk) {
            float4 wa = *(const float4*)&wmat[o * 64 + kk * 32 + hi * 4];
            float4 wb = *(const float4*)&wmat[o * 64 + kk * 32 + 16 + hi * 4];
            bf16x8 wf;
            wf[0] = f2bf(wa.x); wf[1] = f2bf(wa.y); wf[2] = f2bf(wa.z); wf[3] = f2bf(wa.w);
            wf[4] = f2bf(wb.x); wf[5] = f2bf(wb.y); wf[6] = f2bf(wb.z); wf[7] = f2bf(wb.w);
            z[ot] = __builtin_amdgcn_mfma_f32_16x16x32_bf16(wf, yf[kk], z[ot], 0, 0, 0);
        }
    }

    #pragma unroll
    for (int ot = 0; ot < 4; ++ot)
        #pragma unroll
        for (int r = 0; r < 4; ++r) {
            int o = ot * 16 + hi * 4 + r;
            int idx = b_off + o * NN + qwave + lo;
            out[idx] = z[ot][r] + wbias[o] + x[idx];
        }
}

// ---------------------------------------------------------------------------
// Ultimate fallback (no workspace): round-1 single-kernel path.
// ---------------------------------------------------------------------------
__global__ __launch_bounds__(256) void attn_nl_kernel(
    const float* __restrict__ x, const float* __restrict__ wmat,
    const float* __restrict__ wbias, float* __restrict__ out)
{
    __shared__ short Xcj[64 * 64];
    __shared__ short Xjc[64 * 64];
    __shared__ short Plds[4][16 * 64];

    const int tid  = threadIdx.x;
    const int lane = tid & 63;
    const int wv   = tid >> 6;
    const int lo   = lane & 15;
    const int hi   = lane >> 4;

    const int batch = blockIdx.y;
    const int b_off = batch * NC * NN;
    const int qwave = blockIdx.x * 64 + wv * 16;
    const int qrow  = qwave + lo;

    bf16x8 qf[2];
    #pragma unroll
    for (int kk = 0; kk < 2; ++kk)
        #pragma unroll
        for (int e = 0; e < 8; ++e) {
            int c = kk * 32 + hi * 8 + e;
            qf[kk][e] = f2bf(x[b_off + c * NN + qrow]);
        }

    f32x4 acc[4];
    #pragma unroll
    for (int ct = 0; ct < 4; ++ct)
        #pragma unroll
        for (int r = 0; r < 4; ++r) acc[ct][r] = 0.0f;
    float mrow[4], lrow[4];
    #pragma unroll
    for (int r = 0; r < 4; ++r) { mrow[r] = -INFINITY; lrow[r] = 0.0f; }

    const int sc = tid >> 2;
    const int sq = tid & 3;
    const float* xrow = x + b_off + sc * NN + sq * 16;

    for (int jb = 0; jb < NKV; ++jb) {
        const int jbase = jb * 64;
        __syncthreads();

        float fl[16];
        *(float4*)&fl[0]  = *(const float4*)(xrow + jbase + 0);
        *(float4*)&fl[4]  = *(const float4*)(xrow + jbase + 4);
        *(float4*)&fl[8]  = *(const float4*)(xrow + jbase + 8);
        *(float4*)&fl[12] = *(const float4*)(xrow + jbase + 12);
        short h[16];
        #pragma unroll
        for (int e = 0; e < 16; ++e) h[e] = f2bf(fl[e]);

        {
            bf16x8 v0, v1;
            #pragma unroll
            for (int e = 0; e < 8; ++e) { v0[e] = h[e]; v1[e] = h[8 + e]; }
            int base = sc * 64 + sq * 16;
            int sw = (sc & 7) << 3;
            *(bf16x8*)&Xcj[(base) ^ sw]     = v0;
            *(bf16x8*)&Xcj[(base + 8) ^ sw] = v1;
        }
        #pragma unroll
        for (int jj = 0; jj < 16; ++jj) {
            int j = sq * 16 + jj;
            Xjc[(j * 64 + sc) ^ ((j & 7) << 3)] = h[jj];
        }
        __syncthreads();

        f32x4 s[4];
        #pragma unroll
        for (int jt = 0; jt < 4; ++jt) {
            #pragma unroll
            for (int r = 0; r < 4; ++r) s[jt][r] = 0.0f;
            int j = jt * 16 + lo;
            #pragma unroll
            for (int kk = 0; kk < 2; ++kk) {
                bf16x8 kf = *(const bf16x8*)&Xjc[(j * 64 + kk * 32 + hi * 8) ^ ((j & 7) << 3)];
                s[jt] = __builtin_amdgcn_mfma_f32_16x16x32_bf16(qf[kk], kf, s[jt], 0, 0, 0);
            }
        }

        float tm[4];
        #pragma unroll
        for (int r = 0; r < 4; ++r)
            tm[r] = fmaxf(fmaxf(s[0][r], s[1][r]), fmaxf(s[2][r], s[3][r]));
        #pragma unroll
        for (int d = 1; d < 16; d <<= 1)
            #pragma unroll
            for (int r = 0; r < 4; ++r)
                tm[r] = fmaxf(tm[r], __shfl_xor(tm[r], d));

        float scl4[4];
        #pragma unroll
        for (int r = 0; r < 4; ++r) {
            float mnew = fmaxf(mrow[r], tm[r]);
            scl4[r] = __expf(mrow[r] - mnew);
            mrow[r] = mnew;
        }

        float rs[4] = {0.f, 0.f, 0.f, 0.f};
        #pragma unroll
        for (int jt = 0; jt < 4; ++jt)
            #pragma unroll
            for (int r = 0; r < 4; ++r) {
                float p = __expf(s[jt][r] - mrow[r]);
                rs[r] += p;
                int i = hi * 4 + r;
                Plds[wv][(i * 64 + jt * 16 + lo) ^ ((i & 7) << 3)] = f2bf(p);
            }
        #pragma unroll
        for (int d = 1; d < 16; d <<= 1)
            #pragma unroll
            for (int r = 0; r < 4; ++r)
                rs[r] += __shfl_xor(rs[r], d);
        #pragma unroll
        for (int r = 0; r < 4; ++r)
            lrow[r] = lrow[r] * scl4[r] + rs[r];

        {
            int srcl = (lo >> 2) << 4;
            float b0 = __shfl(scl4[0], srcl), b1 = __shfl(scl4[1], srcl);
            float b2 = __shfl(scl4[2], srcl), b3 = __shfl(scl4[3], srcl);
            int rr = lo & 3;
            float scl = rr == 0 ? b0 : rr == 1 ? b1 : rr == 2 ? b2 : b3;
            #pragma unroll
            for (int ct = 0; ct < 4; ++ct)
                #pragma unroll
                for (int r = 0; r < 4; ++r) acc[ct][r] *= scl;
        }

        asm volatile("s_waitcnt lgkmcnt(0)" ::: "memory");

        bf16x8 pf[2];
        #pragma unroll
        for (int kk = 0; kk < 2; ++kk)
            pf[kk] = *(const bf16x8*)&Plds[wv][(lo * 64 + kk * 32 + hi * 8) ^ ((lo & 7) << 3)];
        #pragma unroll
        for (int ct = 0; ct < 4; ++ct) {
            int c = ct * 16 + lo;
            #pragma unroll
            for (int kk = 0; kk < 2; ++kk) {
                bf16x8 vf = *(const bf16x8*)&Xcj[(c * 64 + kk * 32 + hi * 8) ^ ((c & 7) << 3)];
                acc[ct] = __builtin_amdgcn_mfma_f32_16x16x32_bf16(vf, pf[kk], acc[ct], 0, 0, 0);
            }
        }
    }

    float linv;
    {
        int srcl = (lo >> 2) << 4;
        float c0 = __shfl(lrow[0], srcl), c1 = __shfl(lrow[1], srcl);
        float c2 = __shfl(lrow[2], srcl), c3 = __shfl(lrow[3], srcl);
        int rr = lo & 3;
        float li = rr == 0 ? c0 : rr == 1 ? c1 : rr == 2 ? c2 : c3;
        linv = 1.0f / li;
    }

    bf16x8 yf[2];
    #pragma unroll
    for (int kk = 0; kk < 2; ++kk)
        #pragma unroll
        for (int e = 0; e < 8; ++e)
            yf[kk][e] = f2bf(acc[kk * 2 + (e >> 2)][e & 3] * linv);

    f32x4 z[4];
    #pragma unroll
    for (int ot = 0; ot < 4; ++ot) {
        #pragma unroll
        for (int r = 0; r < 4; ++r) z[ot][r] = 0.0f;
        int o = ot * 16 + lo;
        #pragma unroll
        for (int kk = 0; kk < 2; ++kk) {
            float4 wa = *(const float4*)&wmat[o * 64 + kk * 32 + hi * 4];
            float4 wb = *(const float4*)&wmat[o * 64 + kk * 32 + 16 + hi * 4];
            bf16x8 wf;
            wf[0] = f2bf(wa.x); wf[1] = f2bf(wa.y); wf[2] = f2bf(wa.z); wf[3] = f2bf(wa.w);
            wf[4] = f2bf(wb.x); wf[5] = f2bf(wb.y); wf[6] = f2bf(wb.z); wf[7] = f2bf(wb.w);
            z[ot] = __builtin_amdgcn_mfma_f32_16x16x32_bf16(wf, yf[kk], z[ot], 0, 0, 0);
        }
    }

    #pragma unroll
    for (int ot = 0; ot < 4; ++ot)
        #pragma unroll
        for (int r = 0; r < 4; ++r) {
            int o = ot * 16 + hi * 4 + r;
            int idx = b_off + o * NN + qwave + lo;
            out[idx] = z[ot][r] + wbias[o] + x[idx];
        }
}

extern "C" void kernel_launch(void* const* d_in, const int* in_sizes, int n_in,
                              void* d_out, int out_size, void* d_ws, size_t ws_size,
                              hipStream_t stream) {
    const float* x  = (const float*)d_in[0];
    const float* w  = (const float*)d_in[1];
    const float* b  = (const float*)d_in[2];
    float* out = (float*)d_out;

    const size_t xhalf = (size_t)2 * NC * NN;   // shorts per orientation (both batches)
    auto need = [&](int ns) -> size_t {
        return xhalf * 2 * sizeof(short)
             + (size_t)ns * 2 * NC * NN * sizeof(float)
             + (size_t)ns * 2 * NN * sizeof(float);
    };

    int ns = 0;
    if      (ws_size >= need(8)) ns = 8;   // 1024 blocks -> 4 blocks/CU
    else if (ws_size >= need(4)) ns = 4;   // = R5 exactly
    else if (ws_size >= need(2)) ns = 2;
    else if (ws_size >= need(1)) ns = 1;

    if (ns) {
        short* Xjc = (short*)d_ws;
        short* Xcj = Xjc + xhalf;
        float* ypart = (float*)(Xcj + xhalf);
        float* lpart = ypart + (size_t)ns * 2 * NC * NN;
        const int tps = NKV / ns;
        prep_kernel<<<dim3(NKV, 2), 256, 0, stream>>>(x, Xjc, Xcj);
        attn_fd_kernel<<<dim3(NN / 128, 2, ns), 256, 0, stream>>>(Xjc, Xcj, ypart, lpart, tps);
        combine_kernel<<<dim3(NN / 64, 2), 256, 0, stream>>>(x, w, b, ypart, lpart, out, ns);
    } else {
        attn_nl_kernel<<<dim3(NN / 64, 2), 256, 0, stream>>>(x, w, b, out);
    }
}